// Round 16
// baseline (546.043 us; speedup 1.0000x reference)
//
#include <hip/hip_runtime.h>

// ---------------- dtype helpers ----------------
__device__ __forceinline__ float b2f(unsigned short u) {
  return __uint_as_float(((unsigned)u) << 16);
}
__device__ __forceinline__ unsigned short f2b(float f) {
  unsigned u = __float_as_uint(f);
  return (unsigned short)((u + 0x7FFFu + ((u >> 16) & 1u)) >> 16);
}
// load element i of a tensor that is bf16 (isb=1) or fp32 (isb=0)
__device__ __forceinline__ float gload(const void* p, int i, int isb) {
  return isb ? b2f(((const unsigned short*)p)[i]) : ((const float*)p)[i];
}
// monotone bijection float -> uint32 (order-preserving incl. negatives)
__device__ __forceinline__ unsigned tokey(float f) {
  unsigned u = __float_as_uint(f);
  return u ^ (unsigned)(((int)u >> 31) | 0x80000000u);
}

// ---------------- dtype detector (r15-proven; single early s_load of *flag
// downstream is the fast isb form -- r14 in-kernel derivation cost +49us) ----------------
__global__ void k_detect(const void* x, int* flag) {
  int tid = threadIdx.x;  // 1 wave
  unsigned short u = ((const unsigned short*)x)[2 * tid];
  int e = (u >> 7) & 0xFF;
  bool sane = (e >= 100 && e <= 140);
  unsigned long long m = __ballot(sane);
  if (tid == 0) *flag = (__popcll(m) >= 40) ? 1 : 0;
}

// ---------------- k_convprep: conv5x5+pool+kwinners FUSED with WtF transpose ----------------
// r15 ledger: k_prep (~25-40us, memory-bound transpose) serialized against
// k_conv (159us, VALUBusy 93%, occupancy-capped 31%) despite zero data
// dependency. v16 fuses prep in as blocks 4096..6399 (block-uniform branch):
// memory-bound prep blocks co-schedule with VALU-saturated conv blocks, so
// prep's HBM stalls hide under conv issue pressure. The prep path REUSES
// conv's pooled[] LDS as its 64x65 tile (16.6KB <= 36.9KB) => fused LDS
// stays 40960B and conv occupancy is unchanged. Conv body byte-identical
// to the r10-frozen form (ladder: r3 204 -> r8 168 -> r9 163 -> r10 160 ->
// r15 159us). wcnt packing: hi16 = cut = #winners with o<4608 (waves 0/1).
__global__ __launch_bounds__(256) void k_convprep(const void* __restrict__ x,
                                                  const void* __restrict__ c1w_g,
                                                  const void* __restrict__ c1b_g,
                                                  const void* __restrict__ duty_g,
                                                  int2* __restrict__ wpair,
                                                  int* __restrict__ wcnt,
                                                  const void* __restrict__ fc1w,
                                                  const void* __restrict__ mraw,
                                                  float* __restrict__ WtF,
                                                  const int* __restrict__ flag) {
  // img[784] floats (3136B) unioned with hist2[2][256] (2048B): img is dead
  // after the post-conv __syncthreads; hist writes all come after it.
  __shared__ __align__(16) unsigned char u_imghist[3136];
  __shared__ float cb[64], bcs[64];
  __shared__ __align__(16) float pooled[9216];
  __shared__ unsigned wtot[4];
  __shared__ unsigned selb, selk;
  float* img = (float*)u_imghist;
  unsigned* h2a = (unsigned*)u_imghist;           // hist2[0]
  unsigned* h2b = (unsigned*)(u_imghist + 1024);  // hist2[1]
  const int tid = threadIdx.x;
  const int isb = *flag;
  const int lane = tid & 63;
  const int wv_id = tid >> 6;

  if (blockIdx.x >= 4096) {
    // ---- PREP path: WtF[i][u] = fc1_w[u][i] * (mask<0.5), transposed ----
    // tile lives in pooled's LDS (disjoint per block; 64*65*4 = 16640B)
    const int pb = (int)blockIdx.x - 4096;   // 0..2303
    const int i0 = (pb % 144) * 64;          // K index (9216)
    const int u0 = (pb / 144) * 64;          // unit index (1024)
    float* tile = pooled;                    // [64][65] padded
    const int tx = tid & 63, ty = tid >> 6;
    for (int uu = ty; uu < 64; uu += 4) {
      int gi = (u0 + uu) * 9216 + i0 + tx;
      float wv = gload(fc1w, gi, isb);
      float mv = gload(mraw, gi, isb);
      tile[uu * 65 + tx] = (mv < 0.5f) ? wv : 0.0f;
    }
    __syncthreads();
    for (int ii = ty; ii < 64; ii += 4)
      WtF[(i0 + ii) * 1024 + u0 + tx] = tile[tx * 65 + ii];
    return;
  }

  // ---- CONV path (byte-identical to r15) ----
  const int b = blockIdx.x;

  for (int i = tid; i < 784; i += 256) img[i] = gload(x, b * 784 + i, isb);
  if (tid < 64) {
    cb[tid] = gload(c1b_g, tid, isb);
    float arg = (float)(400.0 / 9216.0) - gload(duty_g, tid, isb);
    bcs[tid] = (float)exp((double)arg);
  }
  __syncthreads();

  // mapping: c = tid>>2 (64), half = tid&1 (2), pg = (tid>>1)&1 (2) -> ph0 = pg*6
  {
    const int c = tid >> 2;
    const int half = tid & 1;
    const int ph0 = ((tid >> 1) & 1) * 6;
    float w[25];
#pragma unroll
    for (int i = 0; i < 25; ++i) w[i] = gload(c1w_g, c * 25 + i, isb);
    const float bias = cb[c];
    float R[6][16];
#pragma unroll
    for (int r = 0; r < 6; ++r) {
      int ir = 2 * ph0 + r;
#pragma unroll
      for (int q = 0; q < 4; ++q)
        ((float4*)&R[r][0])[q] = ((const float4*)img)[ir * 7 + half * 3 + q];
    }
#pragma unroll
    for (int i = 0; i < 6; ++i) {
      const int ph = ph0 + i;
      float a0[12], a1[12];
#pragma unroll
      for (int j = 0; j < 12; ++j) { a0[j] = 0.f; a1[j] = 0.f; }
      // single sequential fmaf chain per conv cell, k = kw*5 + kh order
      // (kh fastest -- Eigen patch linearization) => bit-exact vs reference
#pragma unroll
      for (int kj = 0; kj < 5; ++kj) {       // kw OUTER
#pragma unroll
        for (int kr = 0; kr < 5; ++kr) {     // kh INNER (fastest)
          float wk = w[kr * 5 + kj];
          const float* r0 = &R[(2 * i + kr) % 6][0];
          const float* r1 = &R[(2 * i + kr + 1) % 6][0];
#pragma unroll
          for (int j = 0; j < 12; ++j) {
            a0[j] = fmaf(r0[j + kj], wk, a0[j]);
            a1[j] = fmaf(r1[j + kj], wk, a1[j]);
          }
        }
      }
      int obase = c * 144 + ph * 12 + half * 6;
#pragma unroll
      for (int q = 0; q < 6; ++q) {
        float m = fmaxf(fmaxf(a0[2 * q], a0[2 * q + 1]),
                        fmaxf(a1[2 * q], a1[2 * q + 1]));
        pooled[obase + q] = m + bias;
      }
      if (i < 5) {  // slide: load img rows 2*ph+6, 2*ph+7 over the two oldest
        int ir0 = 2 * ph + 6, ir1 = 2 * ph + 7;
        float* d0 = &R[(2 * i) % 6][0];
        float* d1 = &R[(2 * i + 1) % 6][0];
#pragma unroll
        for (int q = 0; q < 4; ++q) {
          ((float4*)d0)[q] = ((const float4*)img)[ir0 * 7 + half * 3 + q];
          ((float4*)d1)[q] = ((const float4*)img)[ir1 * 7 + half * 3 + q];
        }
      }
    }
  }
  __syncthreads();  // after this barrier img is DEAD -> its LDS becomes hist2

  // compute this thread's 36 select keys ONCE into registers
  unsigned keys[36];
  {
    const float bcf = bcs[tid >> 2];
#pragma unroll
    for (int e4 = 0; e4 < 9; ++e4) {
      float4 pv = ((float4*)pooled)[tid * 9 + e4];
      keys[4 * e4 + 0] = tokey(pv.x * bcf);
      keys[4 * e4 + 1] = tokey(pv.y * bcf);
      keys[4 * e4 + 2] = tokey(pv.z * bcf);
      keys[4 * e4 + 3] = tokey(pv.w * bcf);
    }
  }

  // radix-select the 400th-largest key; 2 split histograms + shfl suffix scan
  unsigned kfix = 0;
  unsigned kk = 400;
  for (int pass = 3; pass >= 0; --pass) {
    const int shift = pass * 8;
    const unsigned himask = (pass == 3) ? 0u : (0xFFFFFFFFu << (shift + 8));
    h2a[tid] = 0;
    h2b[tid] = 0;
    __syncthreads();
    unsigned* myh = (wv_id < 2) ? h2a : h2b;
    if (pass == 3) {
      // run-length aggregated (all-static indices; scalars only)
      unsigned cbin = keys[0] >> 24, ccnt = 1;
#pragma unroll
      for (int e = 1; e < 36; ++e) {
        unsigned bin = keys[e] >> 24;
        if (bin == cbin) {
          ++ccnt;
        } else {
          atomicAdd(&myh[cbin], ccnt);
          cbin = bin;
          ccnt = 1;
        }
      }
      atomicAdd(&myh[cbin], ccnt);
    } else {
#pragma unroll
      for (int e = 0; e < 36; ++e) {
        unsigned key = keys[e];
        if (((key ^ kfix) & himask) == 0)
          atomicAdd(&myh[(key >> shift) & 255u], 1u);
      }
    }
    __syncthreads();
    unsigned own = h2a[tid] + h2b[tid];
    unsigned v = own;
#pragma unroll
    for (int off = 1; off < 64; off <<= 1) {
      unsigned y = __shfl_down(v, off, 64);
      if (lane + off < 64) v += y;
    }
    if (lane == 0) wtot[wv_id] = v;
    __syncthreads();
#pragma unroll
    for (int w2 = 0; w2 < 4; ++w2)
      if (w2 > wv_id) v += wtot[w2];
    unsigned snext = v - own;
    if (v >= kk && snext < kk) {
      selb = (unsigned)tid;
      selk = kk - snext;
    }
    __syncthreads();
    kfix |= selb << shift;
    kk = selk;
    // (5th barrier removed: next pass's zero->sync orders selb/selk reuse)
  }

  // sorted compaction: per-thread count -> shfl prefix scan -> ordered write.
  // keep ALL with key >= kfix (== boosted >= thr bitwise, ties kept like ref)
  unsigned mycnt = 0;
#pragma unroll
  for (int e = 0; e < 36; ++e) mycnt += (keys[e] >= kfix) ? 1u : 0u;
  unsigned px = mycnt;
#pragma unroll
  for (int off = 1; off < 64; off <<= 1) {
    unsigned y = __shfl_up(px, off, 64);
    if (lane >= off) px += y;
  }
  if (lane == 63) wtot[wv_id] = px;
  __syncthreads();
  unsigned base = 0;
#pragma unroll
  for (int w2 = 0; w2 < 4; ++w2)
    if (w2 < wv_id) base += wtot[w2];
  int pos = (int)(base + px - mycnt);  // exclusive prefix
  for (int e = 0; e < 36; ++e) {
    if (keys[e] >= kfix) {
      int o = tid * 36 + e;
      if (pos < 512)
        wpair[b * 512 + pos] = make_int2(__float_as_int(pooled[o]), o << 12);
      ++pos;
    }
  }
  if (tid == 0) {
    unsigned tot = wtot[0] + wtot[1] + wtot[2] + wtot[3];
    unsigned cut = wtot[0] + wtot[1];  // winners with o < 4608
    if (tot > 512u) tot = 512u;
    if (cut > 512u) cut = 512u;
    wcnt[b] = (int)(tot | (cut << 16));
  }
}

// ---------------- k_fc1: K-SPLIT gather, half-range staging (r15-FROZEN) ----------------
// fc1 = 2 passes at ~26 TB/s effective L2 read -- at the practical L2 BW
// ceiling; 7.05 GB gather traffic is algorithmically minimal. Half-range
// staging from packed wcnt. One sequential ascending-o fmaf chain across
// the two passes => bit-exact.
__global__ __launch_bounds__(128) void k_fc1(const float* __restrict__ WtF,
                                             const int2* __restrict__ wpair,
                                             const int* __restrict__ wcnt,
                                             const void* __restrict__ fc1b,
                                             float* __restrict__ h,
                                             const int* __restrict__ flag,
                                             int phase) {
  __shared__ __align__(16) int2 wl[512];
  const int tid = threadIdx.x;  // 0..127
  const int img = blockIdx.x >> 3;
  const int slice = blockIdx.x & 7;
  const int isb = *flag;
  const unsigned wc = (unsigned)wcnt[img];
  const int cnt = (int)(wc & 0xFFFFu);
  const int cut = (int)(wc >> 16);
  const int beg = phase ? cut : 0;
  const int len = (phase ? cnt : cut) - beg;
  const int2* __restrict__ wp = wpair + img * 512 + beg;
  for (int i = tid; i < len; i += 128) wl[i] = wp[i];
  __syncthreads();
  const int u = (slice << 7) + tid;
  const char* __restrict__ Wb = (const char*)WtF + (unsigned)u * 4u;
  const int4* wl4 = (const int4*)wl;  // 2 pairs per int4, 16B-aligned
  float acc = phase ? h[img * 1024 + u] : 0.f;
  int w = 0;
  for (; w + 8 <= len; w += 8) {
    const int b4 = w >> 1;
    int4 q0 = wl4[b4 + 0];
    int4 q1 = wl4[b4 + 1];
    int4 q2 = wl4[b4 + 2];
    int4 q3 = wl4[b4 + 3];
    acc = fmaf(__int_as_float(q0.x), *(const float*)(Wb + (unsigned)q0.y), acc);
    acc = fmaf(__int_as_float(q0.z), *(const float*)(Wb + (unsigned)q0.w), acc);
    acc = fmaf(__int_as_float(q1.x), *(const float*)(Wb + (unsigned)q1.y), acc);
    acc = fmaf(__int_as_float(q1.z), *(const float*)(Wb + (unsigned)q1.w), acc);
    acc = fmaf(__int_as_float(q2.x), *(const float*)(Wb + (unsigned)q2.y), acc);
    acc = fmaf(__int_as_float(q2.z), *(const float*)(Wb + (unsigned)q2.w), acc);
    acc = fmaf(__int_as_float(q3.x), *(const float*)(Wb + (unsigned)q3.y), acc);
    acc = fmaf(__int_as_float(q3.z), *(const float*)(Wb + (unsigned)q3.w), acc);
  }
  for (; w < len; ++w) {
    int2 p = wl[w];
    acc = fmaf(__int_as_float(p.x), *(const float*)(Wb + (unsigned)p.y), acc);
  }
  if (phase)
    h[img * 1024 + u] = acc + gload(fc1b, u, isb);
  else
    h[img * 1024 + u] = acc;
}

// ---------------- k_sel: row-per-wave barrier-free select + in-block bf table (r15-FROZEN) ----------------
__global__ __launch_bounds__(256) void k_sel(const float* __restrict__ h,
                                             const void* __restrict__ dutyfc,
                                             const void* __restrict__ fc2w,
                                             const void* __restrict__ fc2b,
                                             void* __restrict__ out,
                                             const int* __restrict__ flag) {
  __shared__ __align__(16) unsigned whist[4][256];
  __shared__ __align__(16) float bfl[1024];
  const int tid = threadIdx.x;
  const int lane = tid & 63;
  const int wv = tid >> 6;
  const int row = blockIdx.x * 4 + wv;
  const int isb = *flag;
  for (int i = tid; i < 1024; i += 256)
    bfl[i] = (float)exp((double)(0.09765625f - gload(dutyfc, i, isb)));
  __syncthreads();
  unsigned* hist = whist[wv];
  volatile unsigned* vhist = whist[wv];

  // 16 units/lane, u = j*64 + lane (coalesced); keys in registers
  float hv[16];
  unsigned keys[16];
#pragma unroll
  for (int j = 0; j < 16; ++j) {
    float xv = h[row * 1024 + j * 64 + lane];
    hv[j] = xv;
    keys[j] = tokey(xv * bfl[j * 64 + lane]);
  }

  // barrier-free radix select: 100th largest of the wave's 1024 keys
  unsigned kfix = 0, kk = 100;
  for (int pass = 3; pass >= 0; --pass) {
    const int shift = pass * 8;
    const unsigned himask = (pass == 3) ? 0u : (0xFFFFFFFFu << (shift + 8));
    ((uint4*)hist)[lane] = make_uint4(0u, 0u, 0u, 0u);  // 4 bins/lane zeroed
    __builtin_amdgcn_sched_barrier(0);
#pragma unroll
    for (int j = 0; j < 16; ++j) {
      if (((keys[j] ^ kfix) & himask) == 0)
        atomicAdd(&hist[(keys[j] >> shift) & 255u], 1u);
    }
    __builtin_amdgcn_sched_barrier(0);
    unsigned o0 = vhist[4 * lane + 0];
    unsigned o1 = vhist[4 * lane + 1];
    unsigned o2 = vhist[4 * lane + 2];
    unsigned o3 = vhist[4 * lane + 3];
    unsigned lsum = o0 + o1 + o2 + o3;
    unsigned v = lsum;
#pragma unroll
    for (int off = 1; off < 64; off <<= 1) {
      unsigned y = __shfl_down(v, off, 64);
      if (lane + off < 64) v += y;
    }
    const unsigned after = v - lsum;  // sum over lanes > lane
    const unsigned t3 = o3;
    const unsigned t2 = o2 + t3;
    const unsigned t1 = o1 + t2;
    const unsigned t0 = o0 + t1;
    unsigned candb = 0, candk = 0;
    bool found = false;
    const unsigned S0 = after + t0, S1 = after + t1, S2 = after + t2,
                   S3 = after + t3, S4 = after;
    if (S0 >= kk && S1 < kk) { candb = 4u * lane + 0u; candk = kk - S1; found = true; }
    else if (S1 >= kk && S2 < kk) { candb = 4u * lane + 1u; candk = kk - S2; found = true; }
    else if (S2 >= kk && S3 < kk) { candb = 4u * lane + 2u; candk = kk - S3; found = true; }
    else if (S3 >= kk && S4 < kk) { candb = 4u * lane + 3u; candk = kk - S4; found = true; }
    unsigned long long msk = __ballot(found);
    int src = __ffsll((unsigned long long)msk) - 1;  // exactly one bin matches
    candb = __shfl(candb, src, 64);
    candk = __shfl(candk, src, 64);
    kfix |= candb << shift;
    kk = candk;
  }

  // fc2 on kept units (f64), wave butterfly reduce
  double part[10];
#pragma unroll
  for (int c = 0; c < 10; ++c) part[c] = 0.0;
#pragma unroll
  for (int j = 0; j < 16; ++j) {
    if (keys[j] >= kfix) {
      const int u = j * 64 + lane;
      const double hx = (double)hv[j];
#pragma unroll
      for (int c = 0; c < 10; ++c)
        part[c] = fma(hx, (double)gload(fc2w, c * 1024 + u, isb), part[c]);
    }
  }
#pragma unroll
  for (int c = 0; c < 10; ++c) {
    double p = part[c];
#pragma unroll
    for (int off = 32; off > 0; off >>= 1) p += __shfl_xor(p, off);
    part[c] = p + (double)gload(fc2b, c, isb);
  }

  // log_softmax (f64), wave-local; static select chain for per-lane value
  double m = part[0];
#pragma unroll
  for (int c = 1; c < 10; ++c) m = part[c] > m ? part[c] : m;
  double mv = part[0];
#pragma unroll
  for (int c = 1; c < 10; ++c)
    if (lane == c) mv = part[c];
  double e = (lane < 10) ? exp(mv - m) : 0.0;  // 10 exps in parallel
  double sum = 0.0;
#pragma unroll
  for (int c = 0; c < 10; ++c) sum += __shfl(e, c, 64);  // ascending order
  double logs = log(sum);
  if (lane < 10) {
    double o = mv - m - logs;
    if (isb)
      ((unsigned short*)out)[row * 10 + lane] = f2b((float)o);
    else
      ((float*)out)[row * 10 + lane] = (float)o;
  }
}

// ---------------- launch ----------------
extern "C" void kernel_launch(void* const* d_in, const int* in_sizes, int n_in,
                              void* d_out, int out_size, void* d_ws, size_t ws_size,
                              hipStream_t stream) {
  // ws layout (bytes):
  //   WtF   : 9216*1024*4 = 37,748,736  @ 0
  //   wpair : 4096*512*8  = 16,777,216  @ 37,748,736
  //   wcnt  : 4096*4      =     16,384  @ 54,525,952   (lo16 = cnt, hi16 = cut)
  //   h     : 4096*1024*4 = 16,777,216  @ 54,542,336
  //   flag  : 4                         @ 71,319,552
  char* ws = (char*)d_ws;
  float* WtF = (float*)ws;
  int2* wpair = (int2*)(ws + 37748736);
  int* wcnt = (int*)(ws + 54525952);
  float* h = (float*)(ws + 54542336);
  int* flag = (int*)(ws + 71319552);

  k_detect<<<1, 64, 0, stream>>>(d_in[0], flag);
  // blocks 0..4095 = conv images; 4096..6399 = prep tiles (144*16 = 2304)
  k_convprep<<<4096 + 2304, 256, 0, stream>>>(d_in[0], d_in[1], d_in[2],
                                              d_in[3], wpair, wcnt,
                                              d_in[4], d_in[5], WtF, flag);
  k_fc1<<<4096 * 8, 128, 0, stream>>>(WtF, wpair, wcnt, d_in[6], h, flag, 0);
  k_fc1<<<4096 * 8, 128, 0, stream>>>(WtF, wpair, wcnt, d_in[6], h, flag, 1);
  k_sel<<<1024, 256, 0, stream>>>(h, d_in[7], d_in[8], d_in[9], d_out, flag);
}